// Round 1
// baseline (26122.659 us; speedup 1.0000x reference)
//
#include <hip/hip_runtime.h>
#include <math.h>

#define TSEQ 2048
#define NB   20
#define NIN  256
#define NH   512
#define NOUT 128

typedef unsigned int   u32;
typedef unsigned short u16;
typedef _Float16 f16x2 __attribute__((ext_vector_type(2)));

// LDS layout (dynamic, one extern block)
#define SM_W     0                       // uint2 [32][512]  = 131072 B (LDS-resident weight K-chunk)
#define SM_HBUF  (131072)                // float [512]      = 2048 B
#define SM_HPCK  (131072 + 2048)         // u32   [256]      = 1024 B
#define SM_INP   (131072 + 2048 + 1024)  // u32   [2][256]   = 2048 B
#define SMEM_BYTES (131072 + 2048 + 1024 + 2048)

__device__ __forceinline__ u32 packh2(float a, float b) {
  f16x2 p; p.x = (_Float16)a; p.y = (_Float16)b;
  return __builtin_bit_cast(u32, p);
}

__device__ __forceinline__ float dot2(u32 w, u32 h, float acc) {
#if __has_builtin(__builtin_amdgcn_fdot2)
  return __builtin_amdgcn_fdot2(__builtin_bit_cast(f16x2, w),
                                __builtin_bit_cast(f16x2, h), acc, false);
#else
  f16x2 a = __builtin_bit_cast(f16x2, w), b = __builtin_bit_cast(f16x2, h);
  return acc + (float)a.x * (float)b.x + (float)a.y * (float)b.y;
#endif
}

__device__ __forceinline__ int acq(const int* p) {
  return __hip_atomic_load(p, __ATOMIC_ACQUIRE, __HIP_MEMORY_SCOPE_AGENT);
}
__device__ __forceinline__ void rel(int* p, int v) {
  __hip_atomic_store(p, v, __ATOMIC_RELEASE, __HIP_MEMORY_SCOPE_AGENT);
}

// Persistent fused pipeline. grid = 100 blocks x 512 threads, 1 block/CU.
//  bid  0..39 : pre0 (b = bid>>1, t-half = bid&1)   pre0 = x@Wih0^T + bih0   (f16 out)
//  bid 40..59 : L0   recurrence layer0 (b = bid-40) out0 = h (packed f16 pairs)
//  bid 60..79 : pre1 (b = bid-60)                   pre1 = out0@Wih1^T + bih1 (f16 out)
//  bid 80..99 : L1   recurrence layer1 (b = bid-80) h1f = last h (f32)
__global__ __launch_bounds__(512, 2) void rnn_persist(
    const float* __restrict__ x,    const float* __restrict__ h0,
    const float* __restrict__ Wih0, const float* __restrict__ Whh0,
    const float* __restrict__ bih0, const float* __restrict__ bhh0,
    const float* __restrict__ Wih1, const float* __restrict__ Whh1,
    const float* __restrict__ bih1, const float* __restrict__ bhh1,
    u16* __restrict__ pre0, u32* __restrict__ out0,
    u16* __restrict__ pre1, float* __restrict__ h1f,
    int* __restrict__ flags)
{
  extern __shared__ char smem[];
  uint2* WL   = (uint2*)(smem + SM_W);
  float* hbuf = (float*)(smem + SM_HBUF);
  u32*   hpck = (u32*)  (smem + SM_HPCK);
  u32*   inp  = (u32*)  (smem + SM_INP);

  const int tid = threadIdx.x;
  const int bid = blockIdx.x;
  const int n   = tid;  // output index (one hidden unit per thread)

  if (bid < 40) {
    // ---------------- pre0: x @ Wih0^T + bih0 ----------------
    const int b = bid >> 1, half = bid & 1, t0 = half * 1024;
    u32 wr[128];
    const float4* W4 = (const float4*)(Wih0 + (size_t)n * NIN);
#pragma unroll 8
    for (int j = 0; j < 64; j++) {
      float4 w = W4[j];
      wr[2*j] = packh2(w.x, w.y); wr[2*j+1] = packh2(w.z, w.w);
    }
    const float bias = bih0[n];
    const float* xb = x + ((size_t)b * TSEQ + t0) * NIN;
    u16* op = pre0 + ((size_t)b * TSEQ + t0) * NH;

    float2 r = make_float2(0.f, 0.f);
    if (tid < 128) r = ((const float2*)xb)[tid];
    int cur = 0;
    for (int t = 0; t < 1024; t++) {
      if (tid < 128) inp[cur * 256 + tid] = packh2(r.x, r.y);
      __syncthreads();
      if (t + 1 < 1024 && tid < 128)
        r = ((const float2*)(xb + (size_t)(t + 1) * NIN))[tid];
      float a0 = bias, a1 = 0.f;
      const uint4* xp = (const uint4*)(inp + cur * 256);
#pragma unroll
      for (int j = 0; j < 32; j++) {
        uint4 hv = xp[j];
        a0 = dot2(wr[4*j+0], hv.x, a0); a1 = dot2(wr[4*j+1], hv.y, a1);
        a0 = dot2(wr[4*j+2], hv.z, a0); a1 = dot2(wr[4*j+3], hv.w, a1);
      }
      op[(size_t)t * NH + n] = __builtin_bit_cast(u16, (_Float16)(a0 + a1));
      cur ^= 1;
      if (((t + 1) & 7) == 0) {
        __syncthreads();                 // drain all threads' stores
        if (tid == 0) rel(flags + bid * 32, t + 1);
      }
    }
    return;
  }

  // ---------------- K=512 roles: L0 / pre1 / L1 ----------------
  const int role = (bid - 40) / 20;   // 0 = L0, 1 = pre1, 2 = L1
  const int b    = (bid - 40) % 20;

  const float* Wg; const float* bp;
  if (role == 0)      { Wg = Whh0; bp = bhh0; }
  else if (role == 1) { Wg = Wih1; bp = bih1; }
  else                { Wg = Whh1; bp = bhh1; }

  // Load weights: K 0..383 into 192 VGPR half2; K 384..511 into LDS [32][512] uint2
  u32 wr[192];
  const float4* W4 = (const float4*)(Wg + (size_t)n * NH);
#pragma unroll 8
  for (int j = 0; j < 96; j++) {
    float4 w = W4[j];
    wr[2*j] = packh2(w.x, w.y); wr[2*j+1] = packh2(w.z, w.w);
  }
#pragma unroll 8
  for (int j2 = 0; j2 < 32; j2++) {
    float4 w = W4[96 + j2];
    WL[j2 * NH + n] = make_uint2(packh2(w.x, w.y), packh2(w.z, w.w));
  }
  const float bias = bp[n];

  int* flagOut0 = flags + (40 + b) * 32;
  int* flagPre1 = flags + (60 + b) * 32;

  if (role != 1) {
    // ---------------- recurrence (L0 / L1) ----------------
    const int layer = (role == 0) ? 0 : 1;
    if (tid < 256) {
      float2 hh = ((const float2*)(h0 + ((size_t)layer * NB + b) * NH))[tid];
      hpck[tid] = packh2(hh.x, hh.y);
    }
    __syncthreads();

    const u16* pin = (role == 0 ? pre0 : pre1) + (size_t)b * TSEQ * NH;
    u32* o0p = out0 + (size_t)b * TSEQ * (NH / 2);
    int seen0 = 0, seen1 = 0;
    if (role == 0) { while (seen0 < 1) seen0 = acq(flags + (b * 2 + 0) * 32); }
    else           { while (seen0 < 1) seen0 = acq(flagPre1); }
    u16 pcur = pin[n];

    for (int t = 0; t < TSEQ; t++) {
      u16 pnxt = 0;
      if (t + 1 < TSEQ) {
        if (role == 0) {
          const int hf = (t + 1) >> 10, lc = (t + 1) & 1023;
          if (hf == 0) { while (seen0 < lc + 1) seen0 = acq(flags + (b * 2 + 0) * 32); }
          else         { while (seen1 < lc + 1) seen1 = acq(flags + (b * 2 + 1) * 32); }
        } else {
          while (seen0 < t + 2) seen0 = acq(flagPre1);
        }
        pnxt = pin[(size_t)(t + 1) * NH + n];
      }
      float a0 = bias + (float)__builtin_bit_cast(_Float16, pcur), a1 = 0.f;
      const uint4* hp4 = (const uint4*)hpck;
#pragma unroll
      for (int j = 0; j < 48; j++) {
        uint4 hv = hp4[j];
        a0 = dot2(wr[4*j+0], hv.x, a0); a1 = dot2(wr[4*j+1], hv.y, a1);
        a0 = dot2(wr[4*j+2], hv.z, a0); a1 = dot2(wr[4*j+3], hv.w, a1);
      }
#pragma unroll
      for (int jj = 0; jj < 16; jj++) {
        uint4 hv = hp4[48 + jj];
        uint2 w0 = WL[(2*jj)   * NH + n];
        uint2 w1 = WL[(2*jj+1) * NH + n];
        a0 = dot2(w0.x, hv.x, a0); a1 = dot2(w0.y, hv.y, a1);
        a0 = dot2(w1.x, hv.z, a0); a1 = dot2(w1.y, hv.w, a1);
      }
      const float h = tanhf(a0 + a1);
      hbuf[n] = h;
      __syncthreads();
      if (tid < 256) {
        float2 hh = ((const float2*)hbuf)[tid];
        u32 p = packh2(hh.x, hh.y);
        hpck[tid] = p;
        if (role == 0) o0p[(size_t)t * (NH / 2) + tid] = p;
      }
      if (role == 2 && t == TSEQ - 1) h1f[(size_t)b * NH + n] = h;
      __syncthreads();                 // drains vmcnt for all threads
      if (role == 0 && ((t + 1) & 7) == 0) {
        if (tid == 0) rel(flagOut0, t + 1);
      }
      pcur = pnxt;
    }
  } else {
    // ---------------- pre1: out0 @ Wih1^T + bih1 ----------------
    const u32* ip = out0 + (size_t)b * TSEQ * (NH / 2);
    u16* op = pre1 + (size_t)b * TSEQ * NH;
    int seen = 0;
    while (seen < 1) seen = acq(flagOut0);
    u32 rin = 0;
    if (tid < 256) rin = ip[tid];
    int cur = 0;
    for (int t = 0; t < TSEQ; t++) {
      if (tid < 256) inp[cur * 256 + tid] = rin;
      __syncthreads();
      if (t + 1 < TSEQ) {
        while (seen < t + 2) seen = acq(flagOut0);
        if (tid < 256) rin = ip[(size_t)(t + 1) * (NH / 2) + tid];
      }
      float a0 = bias, a1 = 0.f;
      const uint4* hp4 = (const uint4*)(inp + cur * 256);
#pragma unroll
      for (int j = 0; j < 48; j++) {
        uint4 hv = hp4[j];
        a0 = dot2(wr[4*j+0], hv.x, a0); a1 = dot2(wr[4*j+1], hv.y, a1);
        a0 = dot2(wr[4*j+2], hv.z, a0); a1 = dot2(wr[4*j+3], hv.w, a1);
      }
#pragma unroll
      for (int jj = 0; jj < 16; jj++) {
        uint4 hv = hp4[48 + jj];
        uint2 w0 = WL[(2*jj)   * NH + n];
        uint2 w1 = WL[(2*jj+1) * NH + n];
        a0 = dot2(w0.x, hv.x, a0); a1 = dot2(w0.y, hv.y, a1);
        a0 = dot2(w1.x, hv.z, a0); a1 = dot2(w1.y, hv.w, a1);
      }
      op[(size_t)t * NH + n] = __builtin_bit_cast(u16, (_Float16)(a0 + a1));
      cur ^= 1;
      if (((t + 1) & 7) == 0) {
        __syncthreads();
        if (tid == 0) rel(flagPre1, t + 1);
      }
    }
  }
}

__global__ void fc_kernel(const float* __restrict__ h1f, const float* __restrict__ Wfc,
                          const float* __restrict__ bfc, float* __restrict__ out) {
  const int b = blockIdx.x, o = threadIdx.x;  // 20 blocks x 128 threads
  __shared__ float hs[NH];
  for (int i = o; i < NH; i += NOUT) hs[i] = h1f[(size_t)b * NH + i];
  __syncthreads();
  const float4* w4 = (const float4*)(Wfc + (size_t)o * NH);
  const float4* h4 = (const float4*)hs;
  float acc = bfc[o];
#pragma unroll 8
  for (int j = 0; j < NH / 4; j++) {
    float4 w = w4[j], h = h4[j];
    acc += w.x * h.x + w.y * h.y + w.z * h.z + w.w * h.w;
  }
  out[(size_t)b * NOUT + o] = acc;
}

extern "C" void kernel_launch(void* const* d_in, const int* in_sizes, int n_in,
                              void* d_out, int out_size, void* d_ws, size_t ws_size,
                              hipStream_t stream) {
  const float* x    = (const float*)d_in[0];
  const float* h0   = (const float*)d_in[1];
  const float* Wih0 = (const float*)d_in[2];
  const float* Whh0 = (const float*)d_in[3];
  const float* bih0 = (const float*)d_in[4];
  const float* bhh0 = (const float*)d_in[5];
  const float* Wih1 = (const float*)d_in[6];
  const float* Whh1 = (const float*)d_in[7];
  const float* bih1 = (const float*)d_in[8];
  const float* bhh1 = (const float*)d_in[9];
  const float* Wfc  = (const float*)d_in[10];
  const float* bfc  = (const float*)d_in[11];
  float* out = (float*)d_out;

  char* ws = (char*)d_ws;
  size_t off = 0;
  u16* pre0 = (u16*)(ws + off); off += (size_t)NB * TSEQ * NH * 2;        // 41,943,040
  u32* out0 = (u32*)(ws + off); off += (size_t)NB * TSEQ * (NH / 2) * 4;  // 41,943,040
  u16* pre1 = (u16*)(ws + off); off += (size_t)NB * TSEQ * NH * 2;        // 41,943,040
  float* h1f = (float*)(ws + off); off += (size_t)NB * NH * 4;
  int* flags = (int*)(ws + off);
  const size_t flagbytes = 80 * 32 * sizeof(int);  // one 128B line per flag

  hipMemsetAsync(flags, 0, flagbytes, stream);
  hipFuncSetAttribute((const void*)rnn_persist,
                      hipFuncAttributeMaxDynamicSharedMemorySize, SMEM_BYTES);
  rnn_persist<<<100, 512, SMEM_BYTES, stream>>>(
      x, h0, Wih0, Whh0, bih0, bhh0, Wih1, Whh1, bih1, bhh1,
      pre0, out0, pre1, h1f, flags);
  fc_kernel<<<NB, NOUT, 0, stream>>>(h1f, Wfc, bfc, out);
}

// Round 2
// 4769.464 us; speedup vs baseline: 5.4771x; 5.4771x over previous
//
#include <hip/hip_runtime.h>
#include <math.h>

#define TSEQ 2048
#define NB   20
#define NIN  256
#define NH   512
#define NOUT 128

typedef unsigned int   u32;
typedef unsigned short u16;
typedef _Float16 f16x2 __attribute__((ext_vector_type(2)));

// LDS layout (dynamic, one extern block)
#define SM_W     0                       // uint2 [32][512]  = 131072 B (LDS-resident weight K-chunk)
#define SM_HBUF  (131072)                // float [512]      = 2048 B
#define SM_HPCK  (131072 + 2048)         // u32   [256]      = 1024 B
#define SM_INP   (131072 + 2048 + 1024)  // u32   [2][256]   = 2048 B
#define SMEM_BYTES (131072 + 2048 + 1024 + 2048)

__device__ __forceinline__ u32 packh2(float a, float b) {
  f16x2 p; p.x = (_Float16)a; p.y = (_Float16)b;
  return __builtin_bit_cast(u32, p);
}

__device__ __forceinline__ float dot2(u32 w, u32 h, float acc) {
#if __has_builtin(__builtin_amdgcn_fdot2)
  return __builtin_amdgcn_fdot2(__builtin_bit_cast(f16x2, w),
                                __builtin_bit_cast(f16x2, h), acc, false);
#else
  f16x2 a = __builtin_bit_cast(f16x2, w), b = __builtin_bit_cast(f16x2, h);
  return acc + (float)a.x * (float)b.x + (float)a.y * (float)b.y;
#endif
}

__device__ __forceinline__ int acq(const int* p) {
  return __hip_atomic_load(p, __ATOMIC_ACQUIRE, __HIP_MEMORY_SCOPE_AGENT);
}
__device__ __forceinline__ void rel(int* p, int v) {
  __hip_atomic_store(p, v, __ATOMIC_RELEASE, __HIP_MEMORY_SCOPE_AGENT);
}

// Persistent fused pipeline. grid = 100 blocks x 512 threads, 1 block/CU.
//  bid  0..39 : pre0 (b = bid>>1, t-half = bid&1)   pre0 = x@Wih0^T + bih0   (f16 out)
//  bid 40..59 : L0   recurrence layer0 (b = bid-40) out0 = h (packed f16 pairs)
//  bid 60..79 : pre1 (b = bid-60)                   pre1 = out0@Wih1^T + bih1 (f16 out)
//  bid 80..99 : L1   recurrence layer1 (b = bid-80) h1f = last h (f32)
__global__ __launch_bounds__(512, 2) void rnn_persist(
    const float* __restrict__ x,    const float* __restrict__ h0,
    const float* __restrict__ Wih0, const float* __restrict__ Whh0,
    const float* __restrict__ bih0, const float* __restrict__ bhh0,
    const float* __restrict__ Wih1, const float* __restrict__ Whh1,
    const float* __restrict__ bih1, const float* __restrict__ bhh1,
    u16* __restrict__ pre0, u32* __restrict__ out0,
    u16* __restrict__ pre1, float* __restrict__ h1f,
    int* __restrict__ flags)
{
  extern __shared__ char smem[];
  uint2* WL   = (uint2*)(smem + SM_W);
  float* hbuf = (float*)(smem + SM_HBUF);
  u32*   hpck = (u32*)  (smem + SM_HPCK);
  u32*   inp  = (u32*)  (smem + SM_INP);

  const int tid = threadIdx.x;
  const int bid = blockIdx.x;
  const int n   = tid;  // output index (one hidden unit per thread)

  if (bid < 40) {
    // ---------------- pre0: x @ Wih0^T + bih0 ----------------
    const int b = bid >> 1, half = bid & 1, t0 = half * 1024;
    // FULL unroll: every index into wr must be compile-time, else the array
    // is demoted to scratch (rule #20; round-1 showed VGPR=36 + 26ms).
    u32 wr[128];
    const float4* W4 = (const float4*)(Wih0 + (size_t)n * NIN);
#pragma unroll
    for (int j = 0; j < 64; j++) {
      float4 w = W4[j];
      wr[2*j] = packh2(w.x, w.y); wr[2*j+1] = packh2(w.z, w.w);
    }
    const float bias = bih0[n];
    const float* xb = x + ((size_t)b * TSEQ + t0) * NIN;
    u16* op = pre0 + ((size_t)b * TSEQ + t0) * NH;

    float2 r = make_float2(0.f, 0.f);
    if (tid < 128) r = ((const float2*)xb)[tid];
    int cur = 0;
    for (int t = 0; t < 1024; t++) {
      if (tid < 128) inp[cur * 256 + tid] = packh2(r.x, r.y);
      __syncthreads();
      if (t + 1 < 1024 && tid < 128)
        r = ((const float2*)(xb + (size_t)(t + 1) * NIN))[tid];
      float a0 = bias, a1 = 0.f;
      const uint4* xp = (const uint4*)(inp + cur * 256);
#pragma unroll
      for (int j = 0; j < 32; j++) {
        uint4 hv = xp[j];
        a0 = dot2(wr[4*j+0], hv.x, a0); a1 = dot2(wr[4*j+1], hv.y, a1);
        a0 = dot2(wr[4*j+2], hv.z, a0); a1 = dot2(wr[4*j+3], hv.w, a1);
      }
      op[(size_t)t * NH + n] = __builtin_bit_cast(u16, (_Float16)(a0 + a1));
      cur ^= 1;
      if (((t + 1) & 7) == 0) {
        __syncthreads();                 // drain all threads' stores
        if (tid == 0) rel(flags + bid * 32, t + 1);
      }
    }
    return;
  }

  // ---------------- K=512 roles: L0 / pre1 / L1 ----------------
  const int role = (bid - 40) / 20;   // 0 = L0, 1 = pre1, 2 = L1
  const int b    = (bid - 40) % 20;

  const float* Wg; const float* bp;
  if (role == 0)      { Wg = Whh0; bp = bhh0; }
  else if (role == 1) { Wg = Wih1; bp = bih1; }
  else                { Wg = Whh1; bp = bhh1; }

  // Load weights: K 0..383 into 192 VGPR half2; K 384..511 into LDS [32][512] uint2
  // FULL unroll (compile-time indices) so wr stays in VGPRs.
  u32 wr[192];
  const float4* W4 = (const float4*)(Wg + (size_t)n * NH);
#pragma unroll
  for (int j = 0; j < 96; j++) {
    float4 w = W4[j];
    wr[2*j] = packh2(w.x, w.y); wr[2*j+1] = packh2(w.z, w.w);
  }
#pragma unroll
  for (int j2 = 0; j2 < 32; j2++) {
    float4 w = W4[96 + j2];
    WL[j2 * NH + n] = make_uint2(packh2(w.x, w.y), packh2(w.z, w.w));
  }
  const float bias = bp[n];

  int* flagOut0 = flags + (40 + b) * 32;
  int* flagPre1 = flags + (60 + b) * 32;

  if (role != 1) {
    // ---------------- recurrence (L0 / L1) ----------------
    const int layer = (role == 0) ? 0 : 1;
    if (tid < 256) {
      float2 hh = ((const float2*)(h0 + ((size_t)layer * NB + b) * NH))[tid];
      hpck[tid] = packh2(hh.x, hh.y);
    }
    __syncthreads();

    const u16* pin = (role == 0 ? pre0 : pre1) + (size_t)b * TSEQ * NH;
    u32* o0p = out0 + (size_t)b * TSEQ * (NH / 2);
    int seen0 = 0, seen1 = 0;
    if (role == 0) { while (seen0 < 1) seen0 = acq(flags + (b * 2 + 0) * 32); }
    else           { while (seen0 < 1) seen0 = acq(flagPre1); }
    u16 pcur = pin[n];

    for (int t = 0; t < TSEQ; t++) {
      u16 pnxt = 0;
      if (t + 1 < TSEQ) {
        if (role == 0) {
          const int hf = (t + 1) >> 10, lc = (t + 1) & 1023;
          if (hf == 0) { while (seen0 < lc + 1) seen0 = acq(flags + (b * 2 + 0) * 32); }
          else         { while (seen1 < lc + 1) seen1 = acq(flags + (b * 2 + 1) * 32); }
        } else {
          while (seen0 < t + 2) seen0 = acq(flagPre1);
        }
        pnxt = pin[(size_t)(t + 1) * NH + n];
      }
      float a0 = bias + (float)__builtin_bit_cast(_Float16, pcur), a1 = 0.f;
      const uint4* hp4 = (const uint4*)hpck;
#pragma unroll
      for (int j = 0; j < 48; j++) {
        uint4 hv = hp4[j];
        a0 = dot2(wr[4*j+0], hv.x, a0); a1 = dot2(wr[4*j+1], hv.y, a1);
        a0 = dot2(wr[4*j+2], hv.z, a0); a1 = dot2(wr[4*j+3], hv.w, a1);
      }
#pragma unroll
      for (int jj = 0; jj < 16; jj++) {
        uint4 hv = hp4[48 + jj];
        uint2 w0 = WL[(2*jj)   * NH + n];
        uint2 w1 = WL[(2*jj+1) * NH + n];
        a0 = dot2(w0.x, hv.x, a0); a1 = dot2(w0.y, hv.y, a1);
        a0 = dot2(w1.x, hv.z, a0); a1 = dot2(w1.y, hv.w, a1);
      }
      const float h = tanhf(a0 + a1);
      hbuf[n] = h;
      __syncthreads();
      if (tid < 256) {
        float2 hh = ((const float2*)hbuf)[tid];
        u32 p = packh2(hh.x, hh.y);
        hpck[tid] = p;
        if (role == 0) o0p[(size_t)t * (NH / 2) + tid] = p;
      }
      if (role == 2 && t == TSEQ - 1) h1f[(size_t)b * NH + n] = h;
      __syncthreads();                 // drains vmcnt for all threads
      if (role == 0 && ((t + 1) & 7) == 0) {
        if (tid == 0) rel(flagOut0, t + 1);
      }
      pcur = pnxt;
    }
  } else {
    // ---------------- pre1: out0 @ Wih1^T + bih1 ----------------
    const u32* ip = out0 + (size_t)b * TSEQ * (NH / 2);
    u16* op = pre1 + (size_t)b * TSEQ * NH;
    int seen = 0;
    while (seen < 1) seen = acq(flagOut0);
    u32 rin = 0;
    if (tid < 256) rin = ip[tid];
    int cur = 0;
    for (int t = 0; t < TSEQ; t++) {
      if (tid < 256) inp[cur * 256 + tid] = rin;
      __syncthreads();
      if (t + 1 < TSEQ) {
        while (seen < t + 2) seen = acq(flagOut0);
        if (tid < 256) rin = ip[(size_t)(t + 1) * (NH / 2) + tid];
      }
      float a0 = bias, a1 = 0.f;
      const uint4* hp4 = (const uint4*)(inp + cur * 256);
#pragma unroll
      for (int j = 0; j < 48; j++) {
        uint4 hv = hp4[j];
        a0 = dot2(wr[4*j+0], hv.x, a0); a1 = dot2(wr[4*j+1], hv.y, a1);
        a0 = dot2(wr[4*j+2], hv.z, a0); a1 = dot2(wr[4*j+3], hv.w, a1);
      }
#pragma unroll
      for (int jj = 0; jj < 16; jj++) {
        uint4 hv = hp4[48 + jj];
        uint2 w0 = WL[(2*jj)   * NH + n];
        uint2 w1 = WL[(2*jj+1) * NH + n];
        a0 = dot2(w0.x, hv.x, a0); a1 = dot2(w0.y, hv.y, a1);
        a0 = dot2(w1.x, hv.z, a0); a1 = dot2(w1.y, hv.w, a1);
      }
      op[(size_t)t * NH + n] = __builtin_bit_cast(u16, (_Float16)(a0 + a1));
      cur ^= 1;
      if (((t + 1) & 7) == 0) {
        __syncthreads();
        if (tid == 0) rel(flagPre1, t + 1);
      }
    }
  }
}

__global__ void fc_kernel(const float* __restrict__ h1f, const float* __restrict__ Wfc,
                          const float* __restrict__ bfc, float* __restrict__ out) {
  const int b = blockIdx.x, o = threadIdx.x;  // 20 blocks x 128 threads
  __shared__ float hs[NH];
  for (int i = o; i < NH; i += NOUT) hs[i] = h1f[(size_t)b * NH + i];
  __syncthreads();
  const float4* w4 = (const float4*)(Wfc + (size_t)o * NH);
  const float4* h4 = (const float4*)hs;
  float acc = bfc[o];
#pragma unroll 8
  for (int j = 0; j < NH / 4; j++) {
    float4 w = w4[j], h = h4[j];
    acc += w.x * h.x + w.y * h.y + w.z * h.z + w.w * h.w;
  }
  out[(size_t)b * NOUT + o] = acc;
}

extern "C" void kernel_launch(void* const* d_in, const int* in_sizes, int n_in,
                              void* d_out, int out_size, void* d_ws, size_t ws_size,
                              hipStream_t stream) {
  const float* x    = (const float*)d_in[0];
  const float* h0   = (const float*)d_in[1];
  const float* Wih0 = (const float*)d_in[2];
  const float* Whh0 = (const float*)d_in[3];
  const float* bih0 = (const float*)d_in[4];
  const float* bhh0 = (const float*)d_in[5];
  const float* Wih1 = (const float*)d_in[6];
  const float* Whh1 = (const float*)d_in[7];
  const float* bih1 = (const float*)d_in[8];
  const float* bhh1 = (const float*)d_in[9];
  const float* Wfc  = (const float*)d_in[10];
  const float* bfc  = (const float*)d_in[11];
  float* out = (float*)d_out;

  char* ws = (char*)d_ws;
  size_t off = 0;
  u16* pre0 = (u16*)(ws + off); off += (size_t)NB * TSEQ * NH * 2;        // 41,943,040
  u32* out0 = (u32*)(ws + off); off += (size_t)NB * TSEQ * (NH / 2) * 4;  // 41,943,040
  u16* pre1 = (u16*)(ws + off); off += (size_t)NB * TSEQ * NH * 2;        // 41,943,040
  float* h1f = (float*)(ws + off); off += (size_t)NB * NH * 4;
  int* flags = (int*)(ws + off);
  const size_t flagbytes = 80 * 32 * sizeof(int);  // one 128B line per flag

  hipMemsetAsync(flags, 0, flagbytes, stream);
  hipFuncSetAttribute((const void*)rnn_persist,
                      hipFuncAttributeMaxDynamicSharedMemorySize, SMEM_BYTES);
  rnn_persist<<<100, 512, SMEM_BYTES, stream>>>(
      x, h0, Wih0, Whh0, bih0, bhh0, Wih1, Whh1, bih1, bhh1,
      pre0, out0, pre1, h1f, flags);
  fc_kernel<<<NB, NOUT, 0, stream>>>(h1f, Wfc, bfc, out);
}